// Round 1
// baseline (1054.756 us; speedup 1.0000x reference)
//
#include <hip/hip_runtime.h>
#include <hip/hip_bf16.h>
#include <math.h>

typedef __attribute__((ext_vector_type(4))) float f32x4;
typedef __attribute__((ext_vector_type(8))) __bf16 bf16x8;
typedef __attribute__((ext_vector_type(8))) unsigned short u16x8;

__device__ __forceinline__ unsigned short f2bfu(float f) {
    unsigned u = __builtin_bit_cast(unsigned, f);
    u += 0x7fffu + ((u >> 16) & 1u);   // RNE
    return (unsigned short)(u >> 16);
}

__device__ __forceinline__ bf16x8 cvt_frag(f32x4 a, f32x4 b) {
    u16x8 u;
#pragma unroll
    for (int j = 0; j < 4; ++j) { u[j] = f2bfu(a[j]); u[j + 4] = f2bfu(b[j]); }
    return __builtin_bit_cast(bf16x8, u);
}

// ---------------------------------------------------------------- convs ----
// 6 causal convs (K=7, left pad 6). grid = (64 batches, 6 convs), 256 thr.
struct ConvArgs {
    const float* w[6];
    const float* b[6];
};

__global__ __launch_bounds__(256) void conv_all(const float* __restrict__ X,
                                                ConvArgs args,
                                                float* __restrict__ out) {
    __shared__ float Xs[30][200];
    __shared__ float Wg[30 * 30 * 7];
    const int b = blockIdx.x, j = blockIdx.y;
    const int tid = threadIdx.x;
    const float* xb = X + (size_t)b * 6000;
    for (int i = tid; i < 6000; i += 256) ((float*)Xs)[i] = xb[i];
    const float* wsrc = args.w[j];
    for (int i = tid; i < 6300; i += 256) Wg[i] = wsrc[i];
    __syncthreads();
    const float* bias = args.b[j];
    float* op = out + ((size_t)j * 64 + b) * 6000;
    for (int idx = tid; idx < 6000; idx += 256) {
        const int c = idx / 200, l = idx - c * 200;
        float acc = bias[c];
        const float* wr = &Wg[c * 210];
        if (l >= 6) {
            for (int ci = 0; ci < 30; ++ci) {
                const float* wc = wr + ci * 7;
                const float* xc = &Xs[ci][l - 6];
#pragma unroll
                for (int kk = 0; kk < 7; ++kk) acc += xc[kk] * wc[kk];
            }
        } else {
            for (int ci = 0; ci < 30; ++ci) {
                const float* wc = wr + ci * 7;
#pragma unroll
                for (int kk = 0; kk < 7; ++kk) {
                    const int p = l - 6 + kk;
                    if (p >= 0) acc += Xs[ci][p] * wc[kk];
                }
            }
        }
        op[idx] = acc;
    }
}

// ------------------------------------------------------------ attention ----
// grid = (64 batches, 2 blocks). blk 0: single-head; blk 1: 5 heads (L-chunks).
// Writes sigmoid(attn) + X  into A_lin rows [blk*64 + b].
__global__ __launch_bounds__(256) void attn_k(const float* __restrict__ conv,
                                              const float* __restrict__ X,
                                              float* __restrict__ A_lin) {
    __shared__ float x1s[30][200], x2s[30][200], x3s[30][200];
    __shared__ float S[5][30][30];
    const int b = blockIdx.x, blk = blockIdx.y;
    const int tid = threadIdx.x;
    const float* c1 = conv + (((size_t)blk * 3 + 0) * 64 + b) * 6000;
    const float* c2 = conv + (((size_t)blk * 3 + 1) * 64 + b) * 6000;
    const float* c3 = conv + (((size_t)blk * 3 + 2) * 64 + b) * 6000;
    for (int i = tid; i < 6000; i += 256) {
        ((float*)x1s)[i] = c1[i];
        ((float*)x2s)[i] = c2[i];
        ((float*)x3s)[i] = c3[i];
    }
    __syncthreads();
    const float scale = 7.0710678118654752e-2f;  // 1/sqrt(200), full-L per source
    if (blk == 0) {
        for (int idx = tid; idx < 900; idx += 256) {
            const int c = idx / 30, d = idx - c * 30;
            float acc = 0.f;
            for (int l = 0; l < 200; ++l) acc += x1s[c][l] * x2s[d][l];
            S[0][c][d] = acc * scale;
        }
    } else {
        for (int idx = tid; idx < 4500; idx += 256) {
            const int h = idx / 900, rem = idx - h * 900;
            const int c = rem / 30, d = rem - c * 30;
            const int base = h * 40;
            float acc = 0.f;
            for (int k = 0; k < 40; ++k) acc += x1s[c][base + k] * x2s[d][base + k];
            S[h][c][d] = acc * scale;
        }
    }
    __syncthreads();
    for (int idx = tid; idx < 6000; idx += 256) {
        const int c = idx / 200, l = idx - c * 200;
        float acc = 0.f;
        if (blk == 0) {
            for (int d = 0; d < 30; ++d) acc += S[0][c][d] * x3s[d][l];
        } else {
            const int h = l / 40;
            for (int d = 0; d < 30; ++d) acc += S[h][c][d] * x3s[d][l];
        }
        const float v = 1.f / (1.f + __expf(-acc)) + X[(size_t)b * 6000 + idx];
        A_lin[((size_t)blk * 64 + b) * 6000 + idx] = v;
    }
}

// ------------------------------------------------------------------- BN ----
// Stage 1: normalize A_lin in place (bn11 / bn21), also emit bf16 copy.
__global__ __launch_bounds__(256) void bn_stage1(float* __restrict__ A,
                                                 unsigned short* __restrict__ Ab,
                                                 const float* __restrict__ g11,
                                                 const float* __restrict__ b11,
                                                 const float* __restrict__ g21,
                                                 const float* __restrict__ b21) {
    const int c = blockIdx.x, h = blockIdx.y;
    const int tid = threadIdx.x;
    const size_t base = (size_t)h * 64 * 6000 + c * 200;
    float s = 0.f, ss = 0.f;
    for (int i = tid; i < 12800; i += 256) {
        const int b = i / 200, l = i - b * 200;
        const float v = A[base + (size_t)b * 6000 + l];
        s += v; ss += v * v;
    }
    __shared__ float rs[4], rss[4];
    __shared__ float sc_sh, sh_sh;
    for (int off = 32; off > 0; off >>= 1) { s += __shfl_down(s, off); ss += __shfl_down(ss, off); }
    const int wave = tid >> 6, lane = tid & 63;
    if (lane == 0) { rs[wave] = s; rss[wave] = ss; }
    __syncthreads();
    if (tid == 0) {
        const float S = rs[0] + rs[1] + rs[2] + rs[3];
        const float SS = rss[0] + rss[1] + rss[2] + rss[3];
        const float mean = S * (1.f / 12800.f);
        const float var = SS * (1.f / 12800.f) - mean * mean;
        const float* gp = h ? g21 : g11;
        const float* bp = h ? b21 : b11;
        const float scale = gp[c] * rsqrtf(var + 1e-5f);
        sc_sh = scale;
        sh_sh = bp[c] - mean * scale;
    }
    __syncthreads();
    const float scale = sc_sh, shift = sh_sh;
    for (int i = tid; i < 12800; i += 256) {
        const int b = i / 200, l = i - b * 200;
        const size_t idx = base + (size_t)b * 6000 + l;
        const float o = A[idx] * scale + shift;
        A[idx] = o;
        Ab[idx] = f2bfu(o);
    }
}

// Stage 2: bn(A_lin + O) (bn12 / bn22) -> concat layout, bf16.
__global__ __launch_bounds__(256) void bn_stage2(const float* __restrict__ A,
                                                 const float* __restrict__ O,
                                                 unsigned short* __restrict__ Cat,
                                                 const float* __restrict__ g12,
                                                 const float* __restrict__ b12,
                                                 const float* __restrict__ g22,
                                                 const float* __restrict__ b22) {
    const int c = blockIdx.x, h = blockIdx.y;
    const int tid = threadIdx.x;
    const size_t base = (size_t)h * 64 * 6000 + c * 200;
    float s = 0.f, ss = 0.f;
    for (int i = tid; i < 12800; i += 256) {
        const int b = i / 200, l = i - b * 200;
        const size_t idx = base + (size_t)b * 6000 + l;
        const float v = A[idx] + O[idx];
        s += v; ss += v * v;
    }
    __shared__ float rs[4], rss[4];
    __shared__ float sc_sh, sh_sh;
    for (int off = 32; off > 0; off >>= 1) { s += __shfl_down(s, off); ss += __shfl_down(ss, off); }
    const int wave = tid >> 6, lane = tid & 63;
    if (lane == 0) { rs[wave] = s; rss[wave] = ss; }
    __syncthreads();
    if (tid == 0) {
        const float S = rs[0] + rs[1] + rs[2] + rs[3];
        const float SS = rss[0] + rss[1] + rss[2] + rss[3];
        const float mean = S * (1.f / 12800.f);
        const float var = SS * (1.f / 12800.f) - mean * mean;
        const float* gp = h ? g22 : g12;
        const float* bp = h ? b22 : b12;
        const float scale = gp[c] * rsqrtf(var + 1e-5f);
        sc_sh = scale;
        sh_sh = bp[c] - mean * scale;
    }
    __syncthreads();
    const float scale = sc_sh, shift = sh_sh;
    for (int i = tid; i < 12800; i += 256) {
        const int b = i / 200, l = i - b * 200;
        const size_t idx = base + (size_t)b * 6000 + l;
        const float o = (A[idx] + O[idx]) * scale + shift;
        Cat[(size_t)b * 12000 + (size_t)h * 6000 + c * 200 + l] = f2bfu(o);
    }
}

// ----------------------------------------------------------------- GEMM ----
// C[m,n] = sum_k A[m,k]*W[n,k] + bias[n].  A: bf16 [M][K] row-major,
// W: fp32 [N][K] row-major (converted in-flight).  4 waves/block, each wave
// owns MT 16-row m-tiles (M = 64*MT), block covers 16 columns. grid = N/16.
template <int MT, bool OUT_BF16>
__global__ __launch_bounds__(256) void gemm_tn(const unsigned short* __restrict__ A,
                                               const float* __restrict__ W,
                                               const float* __restrict__ bias,
                                               float* __restrict__ Cf,
                                               unsigned short* __restrict__ Cb,
                                               int N, int K) {
    const int tid = threadIdx.x;
    const int wave = tid >> 6;
    const int lane = tid & 63;
    const int r = lane & 15;      // A-row / W-row / D-col within tile
    const int g = lane >> 4;      // k-group (8 elems each)
    const int n0 = blockIdx.x * 16;
    const int m0 = wave * (MT * 16);

    f32x4 acc[MT] = {};
    const u16x8 zu = {};
    const bf16x8 zfrag = __builtin_bit_cast(bf16x8, zu);

    const float* wp = W + (size_t)(n0 + r) * K;
    const unsigned short* ap = A + (size_t)(m0 + r) * K;

    for (int k0 = 0; k0 < K; k0 += 32) {
        const int kk = k0 + g * 8;
        const bool ok = (kk + 8 <= K);  // K%32 is 0 or 16 -> whole frag in/out
        bf16x8 bfrag;
        if (ok) {
            const f32x4* p = reinterpret_cast<const f32x4*>(wp + kk);
            bfrag = cvt_frag(p[0], p[1]);
        } else {
            bfrag = zfrag;
        }
#pragma unroll
        for (int mt = 0; mt < MT; ++mt) {
            bf16x8 afrag;
            if (ok) {
                afrag = __builtin_bit_cast(
                    bf16x8, *reinterpret_cast<const u16x8*>(ap + (size_t)mt * 16 * K + kk));
            } else {
                afrag = zfrag;
            }
            acc[mt] = __builtin_amdgcn_mfma_f32_16x16x32_bf16(afrag, bfrag, acc[mt], 0, 0, 0);
        }
    }

    const float bv = bias[n0 + r];
#pragma unroll
    for (int mt = 0; mt < MT; ++mt) {
#pragma unroll
        for (int rr = 0; rr < 4; ++rr) {
            const int row = m0 + mt * 16 + g * 4 + rr;  // D: row=(lane>>4)*4+reg
            const size_t off = (size_t)row * N + (n0 + r);  // D: col=lane&15
            const float v = acc[mt][rr] + bv;
            if constexpr (OUT_BF16) Cb[off] = f2bfu(v);
            else Cf[off] = v;
        }
    }
}

// ---------------------------------------------------------------- launch ----
extern "C" void kernel_launch(void* const* d_in, const int* in_sizes, int n_in,
                              void* d_out, int out_size, void* d_ws, size_t ws_size,
                              hipStream_t stream) {
    (void)in_sizes; (void)n_in; (void)out_size; (void)ws_size;
    const float* X = (const float*)d_in[0];
    ConvArgs ca;
    for (int j = 0; j < 6; ++j) {
        ca.w[j] = (const float*)d_in[1 + 2 * j];
        ca.b[j] = (const float*)d_in[2 + 2 * j];
    }
    const float* bn11_g = (const float*)d_in[13];
    const float* bn11_b = (const float*)d_in[14];
    const float* bn12_g = (const float*)d_in[15];
    const float* bn12_b = (const float*)d_in[16];
    const float* bn21_g = (const float*)d_in[17];
    const float* bn21_b = (const float*)d_in[18];
    const float* bn22_g = (const float*)d_in[19];
    const float* bn22_b = (const float*)d_in[20];
    const float* lin1_w = (const float*)d_in[21];
    const float* lin1_b = (const float*)d_in[22];
    const float* lin2_w = (const float*)d_in[23];
    const float* lin2_b = (const float*)d_in[24];
    const float* cw = (const float*)d_in[25];
    const float* cb = (const float*)d_in[26];
    float* out = (float*)d_out;

    // workspace layout (bytes):
    //   [0, 9216000)          convout [6][64][30][200] f32
    //     reused after attn:  T_bf16 [128][6000] @0 (1.536 MB),
    //                         O f32  [128][6000] @1536000 (3.072 MB),
    //                         Cat bf16 [64][12000] @4608000 (1.536 MB)
    //   [9216000, 12288000)   A_lin f32 [128][6000]
    //   [12288000, 13824000)  A_bf16 [128][6000]
    char* w = (char*)d_ws;
    float* convout = (float*)w;
    unsigned short* T_bf = (unsigned short*)w;
    float* O = (float*)(w + 1536000);
    unsigned short* Cat = (unsigned short*)(w + 4608000);
    float* A_lin = (float*)(w + 9216000);
    unsigned short* A_bf = (unsigned short*)(w + 12288000);

    conv_all<<<dim3(64, 6), 256, 0, stream>>>(X, ca, convout);
    attn_k<<<dim3(64, 2), 256, 0, stream>>>(convout, X, A_lin);
    bn_stage1<<<dim3(30, 2), 256, 0, stream>>>(A_lin, A_bf, bn11_g, bn11_b, bn21_g, bn21_b);
    // t = A @ lin1^T + lin1_b   (M=128 stacks block1+block2, shared weights)
    gemm_tn<2, true><<<dim3(375), 256, 0, stream>>>(A_bf, lin1_w, lin1_b, nullptr, T_bf, 6000, 6000);
    // o = t @ lin2^T + lin2_b
    gemm_tn<2, false><<<dim3(375), 256, 0, stream>>>(T_bf, lin2_w, lin2_b, O, nullptr, 6000, 6000);
    bn_stage2<<<dim3(30, 2), 256, 0, stream>>>(A_lin, O, Cat, bn12_g, bn12_b, bn22_g, bn22_b);
    // out = Cat @ cw^T + cb
    gemm_tn<1, false><<<dim3(375), 256, 0, stream>>>(Cat, cw, cb, out, nullptr, 6000, 12000);
}

// Round 2
// 698.629 us; speedup vs baseline: 1.5098x; 1.5098x over previous
//
#include <hip/hip_runtime.h>
#include <hip/hip_bf16.h>
#include <math.h>

typedef __attribute__((ext_vector_type(4))) float f32x4;
typedef __attribute__((ext_vector_type(8))) __bf16 bf16x8;
typedef __attribute__((ext_vector_type(8))) unsigned short u16x8;

__device__ __forceinline__ unsigned short f2bfu(float f) {
    unsigned u = __builtin_bit_cast(unsigned, f);
    u += 0x7fffu + ((u >> 16) & 1u);   // RNE
    return (unsigned short)(u >> 16);
}

__device__ __forceinline__ bf16x8 cvt_frag(f32x4 a, f32x4 b) {
    u16x8 u;
#pragma unroll
    for (int j = 0; j < 4; ++j) { u[j] = f2bfu(a[j]); u[j + 4] = f2bfu(b[j]); }
    return __builtin_bit_cast(bf16x8, u);
}

// ---------------------------------------------------------------- convs ----
struct ConvArgs {
    const float* w[6];
    const float* b[6];
};

__global__ __launch_bounds__(256) void conv_all(const float* __restrict__ X,
                                                ConvArgs args,
                                                float* __restrict__ out) {
    __shared__ float Xs[30][200];
    __shared__ float Wg[30 * 30 * 7];
    const int b = blockIdx.x, j = blockIdx.y;
    const int tid = threadIdx.x;
    const float* xb = X + (size_t)b * 6000;
    for (int i = tid; i < 6000; i += 256) ((float*)Xs)[i] = xb[i];
    const float* wsrc = args.w[j];
    for (int i = tid; i < 6300; i += 256) Wg[i] = wsrc[i];
    __syncthreads();
    const float* bias = args.b[j];
    float* op = out + ((size_t)j * 64 + b) * 6000;
    for (int idx = tid; idx < 6000; idx += 256) {
        const int c = idx / 200, l = idx - c * 200;
        float acc = bias[c];
        const float* wr = &Wg[c * 210];
        if (l >= 6) {
            for (int ci = 0; ci < 30; ++ci) {
                const float* wc = wr + ci * 7;
                const float* xc = &Xs[ci][l - 6];
#pragma unroll
                for (int kk = 0; kk < 7; ++kk) acc += xc[kk] * wc[kk];
            }
        } else {
            for (int ci = 0; ci < 30; ++ci) {
                const float* wc = wr + ci * 7;
#pragma unroll
                for (int kk = 0; kk < 7; ++kk) {
                    const int p = l - 6 + kk;
                    if (p >= 0) acc += Xs[ci][p] * wc[kk];
                }
            }
        }
        op[idx] = acc;
    }
}

// ------------------------------------------------------------ attention ----
__global__ __launch_bounds__(256) void attn_k(const float* __restrict__ conv,
                                              const float* __restrict__ X,
                                              float* __restrict__ A_lin) {
    __shared__ float x1s[30][200], x2s[30][200], x3s[30][200];
    __shared__ float S[5][30][30];
    const int b = blockIdx.x, blk = blockIdx.y;
    const int tid = threadIdx.x;
    const float* c1 = conv + (((size_t)blk * 3 + 0) * 64 + b) * 6000;
    const float* c2 = conv + (((size_t)blk * 3 + 1) * 64 + b) * 6000;
    const float* c3 = conv + (((size_t)blk * 3 + 2) * 64 + b) * 6000;
    for (int i = tid; i < 6000; i += 256) {
        ((float*)x1s)[i] = c1[i];
        ((float*)x2s)[i] = c2[i];
        ((float*)x3s)[i] = c3[i];
    }
    __syncthreads();
    const float scale = 7.0710678118654752e-2f;  // 1/sqrt(200)
    if (blk == 0) {
        for (int idx = tid; idx < 900; idx += 256) {
            const int c = idx / 30, d = idx - c * 30;
            float acc = 0.f;
            for (int l = 0; l < 200; ++l) acc += x1s[c][l] * x2s[d][l];
            S[0][c][d] = acc * scale;
        }
    } else {
        for (int idx = tid; idx < 4500; idx += 256) {
            const int h = idx / 900, rem = idx - h * 900;
            const int c = rem / 30, d = rem - c * 30;
            const int base = h * 40;
            float acc = 0.f;
            for (int k = 0; k < 40; ++k) acc += x1s[c][base + k] * x2s[d][base + k];
            S[h][c][d] = acc * scale;
        }
    }
    __syncthreads();
    for (int idx = tid; idx < 6000; idx += 256) {
        const int c = idx / 200, l = idx - c * 200;
        float acc = 0.f;
        if (blk == 0) {
            for (int d = 0; d < 30; ++d) acc += S[0][c][d] * x3s[d][l];
        } else {
            const int h = l / 40;
            for (int d = 0; d < 30; ++d) acc += S[h][c][d] * x3s[d][l];
        }
        const float v = 1.f / (1.f + __expf(-acc)) + X[(size_t)b * 6000 + idx];
        A_lin[((size_t)blk * 64 + b) * 6000 + idx] = v;
    }
}

// ------------------------------------------------------------------- BN ----
__global__ __launch_bounds__(256) void bn_stage1(float* __restrict__ A,
                                                 unsigned short* __restrict__ Ab,
                                                 const float* __restrict__ g11,
                                                 const float* __restrict__ b11,
                                                 const float* __restrict__ g21,
                                                 const float* __restrict__ b21) {
    const int c = blockIdx.x, h = blockIdx.y;
    const int tid = threadIdx.x;
    const size_t base = (size_t)h * 64 * 6000 + c * 200;
    float s = 0.f, ss = 0.f;
    for (int i = tid; i < 12800; i += 256) {
        const int b = i / 200, l = i - b * 200;
        const float v = A[base + (size_t)b * 6000 + l];
        s += v; ss += v * v;
    }
    __shared__ float rs[4], rss[4];
    __shared__ float sc_sh, sh_sh;
    for (int off = 32; off > 0; off >>= 1) { s += __shfl_down(s, off); ss += __shfl_down(ss, off); }
    const int wave = tid >> 6, lane = tid & 63;
    if (lane == 0) { rs[wave] = s; rss[wave] = ss; }
    __syncthreads();
    if (tid == 0) {
        const float S = rs[0] + rs[1] + rs[2] + rs[3];
        const float SS = rss[0] + rss[1] + rss[2] + rss[3];
        const float mean = S * (1.f / 12800.f);
        const float var = SS * (1.f / 12800.f) - mean * mean;
        const float* gp = h ? g21 : g11;
        const float* bp = h ? b21 : b11;
        const float scale = gp[c] * rsqrtf(var + 1e-5f);
        sc_sh = scale;
        sh_sh = bp[c] - mean * scale;
    }
    __syncthreads();
    const float scale = sc_sh, shift = sh_sh;
    for (int i = tid; i < 12800; i += 256) {
        const int b = i / 200, l = i - b * 200;
        const size_t idx = base + (size_t)b * 6000 + l;
        const float o = A[idx] * scale + shift;
        A[idx] = o;
        Ab[idx] = f2bfu(o);
    }
}

__global__ __launch_bounds__(256) void bn_stage2(const float* __restrict__ A,
                                                 const float* __restrict__ O,
                                                 unsigned short* __restrict__ Cat,
                                                 const float* __restrict__ g12,
                                                 const float* __restrict__ b12,
                                                 const float* __restrict__ g22,
                                                 const float* __restrict__ b22) {
    const int c = blockIdx.x, h = blockIdx.y;
    const int tid = threadIdx.x;
    const size_t base = (size_t)h * 64 * 6000 + c * 200;
    float s = 0.f, ss = 0.f;
    for (int i = tid; i < 12800; i += 256) {
        const int b = i / 200, l = i - b * 200;
        const size_t idx = base + (size_t)b * 6000 + l;
        const float v = A[idx] + O[idx];
        s += v; ss += v * v;
    }
    __shared__ float rs[4], rss[4];
    __shared__ float sc_sh, sh_sh;
    for (int off = 32; off > 0; off >>= 1) { s += __shfl_down(s, off); ss += __shfl_down(ss, off); }
    const int wave = tid >> 6, lane = tid & 63;
    if (lane == 0) { rs[wave] = s; rss[wave] = ss; }
    __syncthreads();
    if (tid == 0) {
        const float S = rs[0] + rs[1] + rs[2] + rs[3];
        const float SS = rss[0] + rss[1] + rss[2] + rss[3];
        const float mean = S * (1.f / 12800.f);
        const float var = SS * (1.f / 12800.f) - mean * mean;
        const float* gp = h ? g22 : g12;
        const float* bp = h ? b22 : b12;
        const float scale = gp[c] * rsqrtf(var + 1e-5f);
        sc_sh = scale;
        sh_sh = bp[c] - mean * scale;
    }
    __syncthreads();
    const float scale = sc_sh, shift = sh_sh;
    for (int i = tid; i < 12800; i += 256) {
        const int b = i / 200, l = i - b * 200;
        const size_t idx = base + (size_t)b * 6000 + l;
        const float o = (A[idx] + O[idx]) * scale + shift;
        Cat[(size_t)b * 12000 + (size_t)h * 6000 + c * 200 + l] = f2bfu(o);
    }
}

// -------------------------------------------------------- split-K GEMM ----
// P[s][m][n] = sum over k-chunk s of A[m,k]*W[n,k].
// A: bf16 [M][K] row-major; W: fp32 [N][K] row-major (converted in-flight).
// Block: 4 waves; wave owns MT 16-row m-tiles (M = 64*MT); block covers 16
// W-rows (C columns). grid = (N/16, KS). k-iteration space split across KS.
template <int MT>
__global__ __launch_bounds__(256) void gemm_tn_sk(const unsigned short* __restrict__ A,
                                                  const float* __restrict__ W,
                                                  float* __restrict__ P,
                                                  int N, int K,
                                                  int iters_total, int iters_per) {
    const int tid = threadIdx.x;
    const int wave = tid >> 6;
    const int lane = tid & 63;
    const int r = lane & 15;
    const int g = lane >> 4;
    const int n0 = blockIdx.x * 16;
    const int s = blockIdx.y;
    const int it0 = s * iters_per;
    int it1 = it0 + iters_per;
    if (it1 > iters_total) it1 = iters_total;
    const int m0 = wave * (MT * 16);
    const int M = 4 * MT * 16;

    f32x4 acc[MT] = {};
    const u16x8 zu = {};
    const bf16x8 zfrag = __builtin_bit_cast(bf16x8, zu);

    const float* wp = W + (size_t)(n0 + r) * K;
    const unsigned short* ap = A + (size_t)(m0 + r) * K;

    for (int it = it0; it < it1; ++it) {
        const int kk = it * 32 + g * 8;
        const bool ok = (kk + 8 <= K);
        bf16x8 bfrag;
        if (ok) {
            const f32x4* p = reinterpret_cast<const f32x4*>(wp + kk);
            bfrag = cvt_frag(p[0], p[1]);
        } else {
            bfrag = zfrag;
        }
#pragma unroll
        for (int mt = 0; mt < MT; ++mt) {
            bf16x8 afrag;
            if (ok) {
                afrag = __builtin_bit_cast(
                    bf16x8, *reinterpret_cast<const u16x8*>(ap + (size_t)(mt * 16) * K + kk));
            } else {
                afrag = zfrag;
            }
            acc[mt] = __builtin_amdgcn_mfma_f32_16x16x32_bf16(afrag, bfrag, acc[mt], 0, 0, 0);
        }
    }

    float* Pp = P + (size_t)s * M * N;
#pragma unroll
    for (int mt = 0; mt < MT; ++mt) {
#pragma unroll
        for (int rr = 0; rr < 4; ++rr) {
            const int row = m0 + mt * 16 + g * 4 + rr;
            Pp[(size_t)row * N + (n0 + r)] = acc[mt][rr];
        }
    }
}

// Sum KS partials + bias -> fp32 or bf16.
template <bool OUT_BF16>
__global__ __launch_bounds__(256) void reduce_bias(const float* __restrict__ P,
                                                   const float* __restrict__ bias,
                                                   int KS, int MN, int N,
                                                   float* __restrict__ of,
                                                   unsigned short* __restrict__ ob) {
    for (int idx = blockIdx.x * 256 + threadIdx.x; idx < MN; idx += gridDim.x * 256) {
        float v = bias[idx % N];
        for (int s = 0; s < KS; ++s) v += P[(size_t)s * MN + idx];
        if constexpr (OUT_BF16) ob[idx] = f2bfu(v);
        else of[idx] = v;
    }
}

// ---------------------------------------------- fallback direct GEMM ----
template <int MT, bool OUT_BF16>
__global__ __launch_bounds__(256) void gemm_tn(const unsigned short* __restrict__ A,
                                               const float* __restrict__ W,
                                               const float* __restrict__ bias,
                                               float* __restrict__ Cf,
                                               unsigned short* __restrict__ Cb,
                                               int N, int K) {
    const int tid = threadIdx.x;
    const int wave = tid >> 6;
    const int lane = tid & 63;
    const int r = lane & 15;
    const int g = lane >> 4;
    const int n0 = blockIdx.x * 16;
    const int m0 = wave * (MT * 16);

    f32x4 acc[MT] = {};
    const u16x8 zu = {};
    const bf16x8 zfrag = __builtin_bit_cast(bf16x8, zu);

    const float* wp = W + (size_t)(n0 + r) * K;
    const unsigned short* ap = A + (size_t)(m0 + r) * K;

    for (int k0 = 0; k0 < K; k0 += 32) {
        const int kk = k0 + g * 8;
        const bool ok = (kk + 8 <= K);
        bf16x8 bfrag;
        if (ok) {
            const f32x4* p = reinterpret_cast<const f32x4*>(wp + kk);
            bfrag = cvt_frag(p[0], p[1]);
        } else {
            bfrag = zfrag;
        }
#pragma unroll
        for (int mt = 0; mt < MT; ++mt) {
            bf16x8 afrag;
            if (ok) {
                afrag = __builtin_bit_cast(
                    bf16x8, *reinterpret_cast<const u16x8*>(ap + (size_t)(mt * 16) * K + kk));
            } else {
                afrag = zfrag;
            }
            acc[mt] = __builtin_amdgcn_mfma_f32_16x16x32_bf16(afrag, bfrag, acc[mt], 0, 0, 0);
        }
    }

    const float bv = bias[n0 + r];
#pragma unroll
    for (int mt = 0; mt < MT; ++mt) {
#pragma unroll
        for (int rr = 0; rr < 4; ++rr) {
            const int row = m0 + mt * 16 + g * 4 + rr;
            const size_t off = (size_t)row * N + (n0 + r);
            const float v = acc[mt][rr] + bv;
            if constexpr (OUT_BF16) Cb[off] = f2bfu(v);
            else Cf[off] = v;
        }
    }
}

// ---------------------------------------------------------------- launch ----
extern "C" void kernel_launch(void* const* d_in, const int* in_sizes, int n_in,
                              void* d_out, int out_size, void* d_ws, size_t ws_size,
                              hipStream_t stream) {
    (void)in_sizes; (void)n_in; (void)out_size;
    const float* X = (const float*)d_in[0];
    ConvArgs ca;
    for (int j = 0; j < 6; ++j) {
        ca.w[j] = (const float*)d_in[1 + 2 * j];
        ca.b[j] = (const float*)d_in[2 + 2 * j];
    }
    const float* bn11_g = (const float*)d_in[13];
    const float* bn11_b = (const float*)d_in[14];
    const float* bn12_g = (const float*)d_in[15];
    const float* bn12_b = (const float*)d_in[16];
    const float* bn21_g = (const float*)d_in[17];
    const float* bn21_b = (const float*)d_in[18];
    const float* bn22_g = (const float*)d_in[19];
    const float* bn22_b = (const float*)d_in[20];
    const float* lin1_w = (const float*)d_in[21];
    const float* lin1_b = (const float*)d_in[22];
    const float* lin2_w = (const float*)d_in[23];
    const float* lin2_b = (const float*)d_in[24];
    const float* cw = (const float*)d_in[25];
    const float* cb = (const float*)d_in[26];
    float* out = (float*)d_out;

    // workspace layout (bytes):
    //   A_lin f32 [128][6000]            @ 0          (3,072,000)
    //   A_bf  bf16 [128][6000]           @ 3,072,000  (1,536,000)
    //   U region                         @ 4,608,000  (9,216,000):
    //     phase A: convout [6][64][6000] f32
    //     phase B: T_bf @U+0 (1,536,000), O @U+1,536,000 (3,072,000),
    //              Cat @U+4,608,000 (1,536,000)
    //   P partials                       @ 13,824,000 (rest, adaptive KS)
    char* w = (char*)d_ws;
    float* A_lin = (float*)w;
    unsigned short* A_bf = (unsigned short*)(w + 3072000);
    char* U = w + 4608000;
    float* convout = (float*)U;
    unsigned short* T_bf = (unsigned short*)U;
    float* O = (float*)(U + 1536000);
    unsigned short* Cat = (unsigned short*)(U + 4608000);
    float* P = (float*)(w + 13824000);

    const size_t avail = ws_size > 13824000 ? ws_size - 13824000 : 0;
    int KS12 = (int)(avail / 3072000);  // per-chunk partials: 128*6000*4 B
    if (KS12 > 5) KS12 = 5;
    int KS3 = (int)(avail / 1536000);   // per-chunk partials: 64*6000*4 B
    if (KS3 > 10) KS3 = 10;

    conv_all<<<dim3(64, 6), 256, 0, stream>>>(X, ca, convout);
    attn_k<<<dim3(64, 2), 256, 0, stream>>>(convout, X, A_lin);
    bn_stage1<<<dim3(30, 2), 256, 0, stream>>>(A_lin, A_bf, bn11_g, bn11_b, bn21_g, bn21_b);

    if (KS12 >= 1) {
        const int it_tot = 188;  // ceil(6000/32)
        const int it_per = (it_tot + KS12 - 1) / KS12;
        gemm_tn_sk<2><<<dim3(375, KS12), 256, 0, stream>>>(A_bf, lin1_w, P, 6000, 6000, it_tot, it_per);
        reduce_bias<true><<<dim3(512), 256, 0, stream>>>(P, lin1_b, KS12, 768000, 6000, nullptr, T_bf);
        gemm_tn_sk<2><<<dim3(375, KS12), 256, 0, stream>>>(T_bf, lin2_w, P, 6000, 6000, it_tot, it_per);
        reduce_bias<false><<<dim3(512), 256, 0, stream>>>(P, lin2_b, KS12, 768000, 6000, O, nullptr);
    } else {
        gemm_tn<2, true><<<dim3(375), 256, 0, stream>>>(A_bf, lin1_w, lin1_b, nullptr, T_bf, 6000, 6000);
        gemm_tn<2, false><<<dim3(375), 256, 0, stream>>>(T_bf, lin2_w, lin2_b, O, nullptr, 6000, 6000);
    }

    bn_stage2<<<dim3(30, 2), 256, 0, stream>>>(A_lin, O, Cat, bn12_g, bn12_b, bn22_g, bn22_b);

    if (KS3 >= 1) {
        const int it_tot = 375;  // 12000/32
        const int it_per = (it_tot + KS3 - 1) / KS3;
        gemm_tn_sk<1><<<dim3(375, KS3), 256, 0, stream>>>(Cat, cw, P, 6000, 12000, it_tot, it_per);
        reduce_bias<false><<<dim3(512), 256, 0, stream>>>(P, cb, KS3, 384000, 6000, out, nullptr);
    } else {
        gemm_tn<1, false><<<dim3(375), 256, 0, stream>>>(Cat, cw, cb, out, nullptr, 6000, 12000);
    }
}

// Round 3
// 430.367 us; speedup vs baseline: 2.4508x; 1.6233x over previous
//
#include <hip/hip_runtime.h>
#include <hip/hip_bf16.h>
#include <math.h>

typedef __attribute__((ext_vector_type(4))) float f32x4;
typedef __attribute__((ext_vector_type(8))) __bf16 bf16x8;
typedef __attribute__((ext_vector_type(8))) unsigned short u16x8;

__device__ __forceinline__ unsigned short f2bfu(float f) {
    unsigned u = __builtin_bit_cast(unsigned, f);
    u += 0x7fffu + ((u >> 16) & 1u);   // RNE
    return (unsigned short)(u >> 16);
}

__device__ __forceinline__ bf16x8 to_bf8(f32x4 x, f32x4 y) {
    bf16x8 o;
#pragma unroll
    for (int j = 0; j < 4; ++j) { o[j] = (__bf16)x[j]; o[j + 4] = (__bf16)y[j]; }
    return o;
}

__device__ __forceinline__ void gload_lds16(const void* g, void* l) {
    __builtin_amdgcn_global_load_lds(
        (__attribute__((address_space(1))) const void*)g,
        (__attribute__((address_space(3))) void*)l, 16, 0, 0);
}

// ---------------------------------------------------------------- convs ----
struct ConvArgs {
    const float* w[6];
    const float* b[6];
};

__global__ __launch_bounds__(256) void conv_all(const float* __restrict__ X,
                                                ConvArgs args,
                                                float* __restrict__ out) {
    __shared__ float Xs[30][200];
    __shared__ float Wg[30 * 30 * 7];
    const int b = blockIdx.x, j = blockIdx.y;
    const int tid = threadIdx.x;
    const float* xb = X + (size_t)b * 6000;
    for (int i = tid; i < 6000; i += 256) ((float*)Xs)[i] = xb[i];
    const float* wsrc = args.w[j];
    for (int i = tid; i < 6300; i += 256) Wg[i] = wsrc[i];
    __syncthreads();
    const float* bias = args.b[j];
    float* op = out + ((size_t)j * 64 + b) * 6000;
    for (int idx = tid; idx < 6000; idx += 256) {
        const int c = idx / 200, l = idx - c * 200;
        float acc = bias[c];
        const float* wr = &Wg[c * 210];
        if (l >= 6) {
            for (int ci = 0; ci < 30; ++ci) {
                const float* wc = wr + ci * 7;
                const float* xc = &Xs[ci][l - 6];
#pragma unroll
                for (int kk = 0; kk < 7; ++kk) acc += xc[kk] * wc[kk];
            }
        } else {
            for (int ci = 0; ci < 30; ++ci) {
                const float* wc = wr + ci * 7;
#pragma unroll
                for (int kk = 0; kk < 7; ++kk) {
                    const int p = l - 6 + kk;
                    if (p >= 0) acc += Xs[ci][p] * wc[kk];
                }
            }
        }
        op[idx] = acc;
    }
}

// ------------------------------------------------------------ attention ----
__global__ __launch_bounds__(256) void attn_k(const float* __restrict__ conv,
                                              const float* __restrict__ X,
                                              float* __restrict__ A_lin) {
    __shared__ float x1s[30][200], x2s[30][200], x3s[30][200];
    __shared__ float S[5][30][30];
    const int b = blockIdx.x, blk = blockIdx.y;
    const int tid = threadIdx.x;
    const float* c1 = conv + (((size_t)blk * 3 + 0) * 64 + b) * 6000;
    const float* c2 = conv + (((size_t)blk * 3 + 1) * 64 + b) * 6000;
    const float* c3 = conv + (((size_t)blk * 3 + 2) * 64 + b) * 6000;
    for (int i = tid; i < 6000; i += 256) {
        ((float*)x1s)[i] = c1[i];
        ((float*)x2s)[i] = c2[i];
        ((float*)x3s)[i] = c3[i];
    }
    __syncthreads();
    const float scale = 7.0710678118654752e-2f;  // 1/sqrt(200)
    if (blk == 0) {
        for (int idx = tid; idx < 900; idx += 256) {
            const int c = idx / 30, d = idx - c * 30;
            float acc = 0.f;
            for (int l = 0; l < 200; ++l) acc += x1s[c][l] * x2s[d][l];
            S[0][c][d] = acc * scale;
        }
    } else {
        for (int idx = tid; idx < 4500; idx += 256) {
            const int h = idx / 900, rem = idx - h * 900;
            const int c = rem / 30, d = rem - c * 30;
            const int base = h * 40;
            float acc = 0.f;
            for (int k = 0; k < 40; ++k) acc += x1s[c][base + k] * x2s[d][base + k];
            S[h][c][d] = acc * scale;
        }
    }
    __syncthreads();
    for (int idx = tid; idx < 6000; idx += 256) {
        const int c = idx / 200, l = idx - c * 200;
        float acc = 0.f;
        if (blk == 0) {
            for (int d = 0; d < 30; ++d) acc += S[0][c][d] * x3s[d][l];
        } else {
            const int h = l / 40;
            for (int d = 0; d < 30; ++d) acc += S[h][c][d] * x3s[d][l];
        }
        const float v = 1.f / (1.f + __expf(-acc)) + X[(size_t)b * 6000 + idx];
        A_lin[((size_t)blk * 64 + b) * 6000 + idx] = v;
    }
}

// ------------------------------------------------------------------- BN ----
__global__ __launch_bounds__(256) void bn_stage1(float* __restrict__ A,
                                                 unsigned short* __restrict__ Ab,
                                                 const float* __restrict__ g11,
                                                 const float* __restrict__ b11,
                                                 const float* __restrict__ g21,
                                                 const float* __restrict__ b21) {
    const int c = blockIdx.x, h = blockIdx.y;
    const int tid = threadIdx.x;
    const size_t base = (size_t)h * 64 * 6000 + c * 200;
    float s = 0.f, ss = 0.f;
    for (int i = tid; i < 12800; i += 256) {
        const int b = i / 200, l = i - b * 200;
        const float v = A[base + (size_t)b * 6000 + l];
        s += v; ss += v * v;
    }
    __shared__ float rs[4], rss[4];
    __shared__ float sc_sh, sh_sh;
    for (int off = 32; off > 0; off >>= 1) { s += __shfl_down(s, off); ss += __shfl_down(ss, off); }
    const int wave = tid >> 6, lane = tid & 63;
    if (lane == 0) { rs[wave] = s; rss[wave] = ss; }
    __syncthreads();
    if (tid == 0) {
        const float S = rs[0] + rs[1] + rs[2] + rs[3];
        const float SS = rss[0] + rss[1] + rss[2] + rss[3];
        const float mean = S * (1.f / 12800.f);
        const float var = SS * (1.f / 12800.f) - mean * mean;
        const float* gp = h ? g21 : g11;
        const float* bp = h ? b21 : b11;
        const float scale = gp[c] * rsqrtf(var + 1e-5f);
        sc_sh = scale;
        sh_sh = bp[c] - mean * scale;
    }
    __syncthreads();
    const float scale = sc_sh, shift = sh_sh;
    for (int i = tid; i < 12800; i += 256) {
        const int b = i / 200, l = i - b * 200;
        const size_t idx = base + (size_t)b * 6000 + l;
        const float o = A[idx] * scale + shift;
        A[idx] = o;
        Ab[idx] = f2bfu(o);
    }
}

__global__ __launch_bounds__(256) void bn_stage2(const float* __restrict__ A,
                                                 const float* __restrict__ O,
                                                 unsigned short* __restrict__ Cat,
                                                 const float* __restrict__ g12,
                                                 const float* __restrict__ b12,
                                                 const float* __restrict__ g22,
                                                 const float* __restrict__ b22) {
    const int c = blockIdx.x, h = blockIdx.y;
    const int tid = threadIdx.x;
    const size_t base = (size_t)h * 64 * 6000 + c * 200;
    float s = 0.f, ss = 0.f;
    for (int i = tid; i < 12800; i += 256) {
        const int b = i / 200, l = i - b * 200;
        const size_t idx = base + (size_t)b * 6000 + l;
        const float v = A[idx] + O[idx];
        s += v; ss += v * v;
    }
    __shared__ float rs[4], rss[4];
    __shared__ float sc_sh, sh_sh;
    for (int off = 32; off > 0; off >>= 1) { s += __shfl_down(s, off); ss += __shfl_down(ss, off); }
    const int wave = tid >> 6, lane = tid & 63;
    if (lane == 0) { rs[wave] = s; rss[wave] = ss; }
    __syncthreads();
    if (tid == 0) {
        const float S = rs[0] + rs[1] + rs[2] + rs[3];
        const float SS = rss[0] + rss[1] + rss[2] + rss[3];
        const float mean = S * (1.f / 12800.f);
        const float var = SS * (1.f / 12800.f) - mean * mean;
        const float* gp = h ? g22 : g12;
        const float* bp = h ? b22 : b12;
        const float scale = gp[c] * rsqrtf(var + 1e-5f);
        sc_sh = scale;
        sh_sh = bp[c] - mean * scale;
    }
    __syncthreads();
    const float scale = sc_sh, shift = sh_sh;
    for (int i = tid; i < 12800; i += 256) {
        const int b = i / 200, l = i - b * 200;
        const size_t idx = base + (size_t)b * 6000 + l;
        const float o = (A[idx] + O[idx]) * scale + shift;
        Cat[(size_t)b * 12000 + (size_t)h * 6000 + c * 200 + l] = f2bfu(o);
    }
}

// ------------------------------------------- LDS-staged split-K GEMM ----
// P[s][m][n] = sum over k-chunk s of A[m,k]*W[n,k].
// A: bf16 [M][K]; W: fp32 [N][K]. Block: 4 waves, BN=64 W-rows (16/wave),
// all M rows per wave (MT m-tiles). W+A tiles staged in LDS (double-buffered)
// via global_load_lds with XOR-swizzled (pre-swizzled-source) layout.
template <int MT>   // M = MT*16
__global__ __launch_bounds__(256) void gemm_lds_sk(const unsigned short* __restrict__ A,
                                                   const float* __restrict__ W,
                                                   float* __restrict__ P,
                                                   int N, int K,
                                                   int iters_total, int iters_per) {
    constexpr int M = MT * 16;
    constexpr int WB = 64 * 32 * 4;   // 8192 B per buffer (64 rows x 128 B)
    constexpr int AB = M * 32 * 2;    // M*64 B per buffer
    constexpr int ACH = AB / 1024;    // A staging chunks of 1 KB
    __shared__ __align__(16) char lds[2][WB + AB];

    const int tid = threadIdx.x;
    const int wave = tid >> 6;
    const int lane = tid & 63;
    const int r = lane & 15;
    const int g = lane >> 4;
    const int n0 = blockIdx.x * 64;
    const int s = blockIdx.y;
    const int it0 = s * iters_per;
    int it1 = it0 + iters_per;
    if (it1 > iters_total) it1 = iters_total;

    f32x4 acc[MT] = {};
    const u16x8 zu = {};
    const bf16x8 zfrag = __builtin_bit_cast(bf16x8, zu);

    auto stage = [&](int buf, int it) {
        const int k0 = it * 32;
        char* base = &lds[buf][0];
        // W: 8 chunks of 1 KB. stored[row][jj] = logical granule jj^(row&7).
        for (int c = wave; c < 8; c += 4) {
            const int slot = c * 64 + lane;
            const int row = slot >> 3, jj = slot & 7;
            const int j = jj ^ (row & 7);
            int kc = k0 + j * 4;
            if (kc + 4 > K) kc = K - 4;           // clamp; zeroed in compute
            int rn = n0 + row;
            if (rn > N - 1) rn = N - 1;
            gload_lds16(W + (size_t)rn * K + kc, base + c * 1024);
        }
        // A: ACH chunks. stored[m][jj] = logical granule jj^((m>>1)&3).
        char* abase = base + WB;
        for (int c = wave; c < ACH; c += 4) {
            const int slot = c * 64 + lane;
            const int m = slot >> 2, jj = slot & 3;
            const int j = jj ^ ((m >> 1) & 3);
            int kc = k0 + j * 8;
            if (kc + 8 > K) kc = K - 8;
            gload_lds16(A + (size_t)m * K + kc, abase + c * 1024);
        }
    };

    auto compute = [&](int buf, int it) {
        const int k0 = it * 32;
        const float* Wb = (const float*)&lds[buf][0];
        const unsigned short* Ab = (const unsigned short*)(&lds[buf][0] + WB);
        const int wr = wave * 16 + r;
        const bool ok = (k0 + g * 8 + 8 <= K);
        bf16x8 bfrag = zfrag;
        if (ok) {
            const f32x4* Wrow = (const f32x4*)(Wb + wr * 32);
            const f32x4 x = Wrow[(2 * g) ^ (r & 7)];
            const f32x4 y = Wrow[(2 * g + 1) ^ (r & 7)];
            bfrag = to_bf8(x, y);
        }
#pragma unroll
        for (int mt = 0; mt < MT; ++mt) {
            const int m = mt * 16 + r;
            bf16x8 afrag = zfrag;
            if (ok) {
                afrag = __builtin_bit_cast(
                    bf16x8,
                    ((const u16x8*)(Ab + (size_t)m * 32))[g ^ ((m >> 1) & 3)]);
            }
            acc[mt] = __builtin_amdgcn_mfma_f32_16x16x32_bf16(afrag, bfrag, acc[mt], 0, 0, 0);
        }
    };

    int cur = 0;
    if (it0 < it1) stage(0, it0);
    __syncthreads();
    for (int it = it0; it < it1; ++it) {
        if (it + 1 < it1) stage(cur ^ 1, it + 1);
        compute(cur, it);
        __syncthreads();
        cur ^= 1;
    }

    float* Pp = P + (size_t)s * M * N;
    const int col = n0 + wave * 16 + r;
#pragma unroll
    for (int mt = 0; mt < MT; ++mt) {
#pragma unroll
        for (int rr = 0; rr < 4; ++rr) {
            const int row = mt * 16 + g * 4 + rr;
            if (col < N) Pp[(size_t)row * N + col] = acc[mt][rr];
        }
    }
}

// Sum KS partials + bias -> fp32 or bf16.
template <bool OUT_BF16>
__global__ __launch_bounds__(256) void reduce_bias(const float* __restrict__ P,
                                                   const float* __restrict__ bias,
                                                   int KS, int MN, int N,
                                                   float* __restrict__ of,
                                                   unsigned short* __restrict__ ob) {
    for (int idx = blockIdx.x * 256 + threadIdx.x; idx < MN; idx += gridDim.x * 256) {
        float v = bias[idx % N];
        for (int s = 0; s < KS; ++s) v += P[(size_t)s * MN + idx];
        if constexpr (OUT_BF16) ob[idx] = f2bfu(v);
        else of[idx] = v;
    }
}

// ---------------------------------------------------------------- launch ----
extern "C" void kernel_launch(void* const* d_in, const int* in_sizes, int n_in,
                              void* d_out, int out_size, void* d_ws, size_t ws_size,
                              hipStream_t stream) {
    (void)in_sizes; (void)n_in; (void)out_size;
    const float* X = (const float*)d_in[0];
    ConvArgs ca;
    for (int j = 0; j < 6; ++j) {
        ca.w[j] = (const float*)d_in[1 + 2 * j];
        ca.b[j] = (const float*)d_in[2 + 2 * j];
    }
    const float* bn11_g = (const float*)d_in[13];
    const float* bn11_b = (const float*)d_in[14];
    const float* bn12_g = (const float*)d_in[15];
    const float* bn12_b = (const float*)d_in[16];
    const float* bn21_g = (const float*)d_in[17];
    const float* bn21_b = (const float*)d_in[18];
    const float* bn22_g = (const float*)d_in[19];
    const float* bn22_b = (const float*)d_in[20];
    const float* lin1_w = (const float*)d_in[21];
    const float* lin1_b = (const float*)d_in[22];
    const float* lin2_w = (const float*)d_in[23];
    const float* lin2_b = (const float*)d_in[24];
    const float* cw = (const float*)d_in[25];
    const float* cb = (const float*)d_in[26];
    float* out = (float*)d_out;

    // workspace layout (bytes):
    //   A_lin f32 [128][6000]            @ 0          (3,072,000)
    //   A_bf  bf16 [128][6000]           @ 3,072,000  (1,536,000)
    //   U region                         @ 4,608,000  (9,216,000):
    //     phase A: convout [6][64][6000] f32
    //     phase B: T_bf @U+0, O @U+1,536,000, Cat @U+4,608,000
    //   P partials                       @ 13,824,000 (rest, adaptive KS)
    char* w = (char*)d_ws;
    float* A_lin = (float*)w;
    unsigned short* A_bf = (unsigned short*)(w + 3072000);
    char* U = w + 4608000;
    float* convout = (float*)U;
    unsigned short* T_bf = (unsigned short*)U;
    float* O = (float*)(U + 1536000);
    unsigned short* Cat = (unsigned short*)(U + 4608000);
    float* P = (float*)(w + 13824000);

    const size_t avail = ws_size > 13824000 ? ws_size - 13824000 : 0;
    int KS12 = (int)(avail / 3072000);  // per-chunk partials: 128*6000*4 B
    if (KS12 > 8) KS12 = 8;
    if (KS12 < 1) KS12 = 1;
    int KS3 = (int)(avail / 1536000);   // per-chunk partials: 64*6000*4 B
    if (KS3 > 12) KS3 = 12;
    if (KS3 < 1) KS3 = 1;

    conv_all<<<dim3(64, 6), 256, 0, stream>>>(X, ca, convout);
    attn_k<<<dim3(64, 2), 256, 0, stream>>>(convout, X, A_lin);
    bn_stage1<<<dim3(30, 2), 256, 0, stream>>>(A_lin, A_bf, bn11_g, bn11_b, bn21_g, bn21_b);

    {
        const int it_tot = 188;  // ceil(6000/32)
        const int it_per = (it_tot + KS12 - 1) / KS12;
        gemm_lds_sk<8><<<dim3(94, KS12), 256, 0, stream>>>(A_bf, lin1_w, P, 6000, 6000, it_tot, it_per);
        reduce_bias<true><<<dim3(512), 256, 0, stream>>>(P, lin1_b, KS12, 768000, 6000, nullptr, T_bf);
        gemm_lds_sk<8><<<dim3(94, KS12), 256, 0, stream>>>(T_bf, lin2_w, P, 6000, 6000, it_tot, it_per);
        reduce_bias<false><<<dim3(512), 256, 0, stream>>>(P, lin2_b, KS12, 768000, 6000, O, nullptr);
    }

    bn_stage2<<<dim3(30, 2), 256, 0, stream>>>(A_lin, O, Cat, bn12_g, bn12_b, bn22_g, bn22_b);

    {
        const int it_tot = 375;  // 12000/32
        const int it_per = (it_tot + KS3 - 1) / KS3;
        gemm_lds_sk<4><<<dim3(94, KS3), 256, 0, stream>>>(Cat, cw, P, 6000, 12000, it_tot, it_per);
        reduce_bias<false><<<dim3(512), 256, 0, stream>>>(P, cb, KS3, 384000, 6000, out, nullptr);
    }
}

// Round 4
// 341.595 us; speedup vs baseline: 3.0877x; 1.2599x over previous
//
#include <hip/hip_runtime.h>
#include <hip/hip_bf16.h>
#include <math.h>

typedef __attribute__((ext_vector_type(4))) float f32x4;
typedef __attribute__((ext_vector_type(8))) __bf16 bf16x8;
typedef __attribute__((ext_vector_type(8))) unsigned short u16x8;

__device__ __forceinline__ unsigned short f2bfu(float f) {
    unsigned u = __builtin_bit_cast(unsigned, f);
    u += 0x7fffu + ((u >> 16) & 1u);   // RNE
    return (unsigned short)(u >> 16);
}

__device__ __forceinline__ bf16x8 to_bf8(f32x4 x, f32x4 y) {
    bf16x8 o;
#pragma unroll
    for (int j = 0; j < 4; ++j) { o[j] = (__bf16)x[j]; o[j + 4] = (__bf16)y[j]; }
    return o;
}

__device__ __forceinline__ void gload_lds16(const void* g, void* l) {
    __builtin_amdgcn_global_load_lds(
        (__attribute__((address_space(1))) const void*)g,
        (__attribute__((address_space(3))) void*)l, 16, 0, 0);
}

// ---------------------------------------------------------------- convs ----
// Register-blocked: thread = (channel c, 25-long L strip). Per ci: 7 W taps +
// 31-value X window in registers -> 175 FMA / 38 LDS reads (conflict-free).
struct ConvArgs {
    const float* w[6];
    const float* b[6];
};

__global__ __launch_bounds__(256) void conv_all(const float* __restrict__ X,
                                                ConvArgs args,
                                                float* __restrict__ out) {
    __shared__ float Xsp[30][208];   // [ci][6 zero-pad + 200 + 2 spare]
    __shared__ float Wg[30][212];    // [c][ci*7+kk]
    const int b = blockIdx.x, j = blockIdx.y;
    const int tid = threadIdx.x;
    const float* xb = X + (size_t)b * 6000;
    for (int i = tid; i < 30 * 208; i += 256) {
        const int ci = i / 208, p = i - ci * 208;
        float v = 0.f;
        if (p >= 6 && p < 206) v = xb[ci * 200 + (p - 6)];
        Xsp[ci][p] = v;
    }
    const float* wsrc = args.w[j];
    for (int i = tid; i < 6300; i += 256) Wg[i / 210][i % 210] = wsrc[i];
    __syncthreads();
    if (tid < 240) {
        const int c = tid >> 3;        // 0..29
        const int strip = tid & 7;     // 0..7
        const int l0 = strip * 25;
        float acc[25];
        const float bias = args.b[j][c];
#pragma unroll
        for (int o = 0; o < 25; ++o) acc[o] = bias;
        for (int ci = 0; ci < 30; ++ci) {
            float wv[7];
#pragma unroll
            for (int kk = 0; kk < 7; ++kk) wv[kk] = Wg[c][ci * 7 + kk];
            float xw[31];
#pragma unroll
            for (int i = 0; i < 31; ++i) xw[i] = Xsp[ci][l0 + i];
#pragma unroll
            for (int o = 0; o < 25; ++o) {
                float a = acc[o];
#pragma unroll
                for (int kk = 0; kk < 7; ++kk) a += xw[o + kk] * wv[kk];
                acc[o] = a;
            }
        }
        float* op = out + ((size_t)j * 64 + b) * 6000 + c * 200 + l0;
#pragma unroll
        for (int o = 0; o < 25; ++o) op[o] = acc[o];
    }
}

// ------------------------------------------------------------ attention ----
__global__ __launch_bounds__(256) void attn_k(const float* __restrict__ conv,
                                              const float* __restrict__ X,
                                              float* __restrict__ A_lin) {
    __shared__ float x1s[30][201], x2s[30][201], x3s[30][201];
    __shared__ float S[5][30][30];
    const int b = blockIdx.x, blk = blockIdx.y;
    const int tid = threadIdx.x;
    const float* c1 = conv + (((size_t)blk * 3 + 0) * 64 + b) * 6000;
    const float* c2 = conv + (((size_t)blk * 3 + 1) * 64 + b) * 6000;
    const float* c3 = conv + (((size_t)blk * 3 + 2) * 64 + b) * 6000;
    for (int i = tid; i < 6000; i += 256) {
        const int c = i / 200, l = i - c * 200;
        x1s[c][l] = c1[i];
        x2s[c][l] = c2[i];
        x3s[c][l] = c3[i];
    }
    __syncthreads();
    const float scale = 7.0710678118654752e-2f;  // 1/sqrt(200)
    if (blk == 0) {
        for (int idx = tid; idx < 900; idx += 256) {
            const int c = idx / 30, d = idx - c * 30;
            float acc = 0.f;
            for (int l = 0; l < 200; ++l) acc += x1s[c][l] * x2s[d][l];
            S[0][c][d] = acc * scale;
        }
    } else {
        for (int idx = tid; idx < 4500; idx += 256) {
            const int h = idx / 900, rem = idx - h * 900;
            const int c = rem / 30, d = rem - c * 30;
            const int base = h * 40;
            float acc = 0.f;
            for (int k = 0; k < 40; ++k) acc += x1s[c][base + k] * x2s[d][base + k];
            S[h][c][d] = acc * scale;
        }
    }
    __syncthreads();
    for (int idx = tid; idx < 6000; idx += 256) {
        const int c = idx / 200, l = idx - c * 200;
        float acc = 0.f;
        if (blk == 0) {
            for (int d = 0; d < 30; ++d) acc += S[0][c][d] * x3s[d][l];
        } else {
            const int h = l / 40;
            for (int d = 0; d < 30; ++d) acc += S[h][c][d] * x3s[d][l];
        }
        const float v = 1.f / (1.f + __expf(-acc)) + X[(size_t)b * 6000 + idx];
        A_lin[((size_t)blk * 64 + b) * 6000 + idx] = v;
    }
}

// ------------------------------------------------------------------- BN ----
__global__ __launch_bounds__(256) void bn_stage1(float* __restrict__ A,
                                                 unsigned short* __restrict__ Ab,
                                                 const float* __restrict__ g11,
                                                 const float* __restrict__ b11,
                                                 const float* __restrict__ g21,
                                                 const float* __restrict__ b21) {
    const int c = blockIdx.x, h = blockIdx.y;
    const int tid = threadIdx.x;
    const size_t base = (size_t)h * 64 * 6000 + c * 200;
    float s = 0.f, ss = 0.f;
    for (int i = tid; i < 12800; i += 256) {
        const int b = i / 200, l = i - b * 200;
        const float v = A[base + (size_t)b * 6000 + l];
        s += v; ss += v * v;
    }
    __shared__ float rs[4], rss[4];
    __shared__ float sc_sh, sh_sh;
    for (int off = 32; off > 0; off >>= 1) { s += __shfl_down(s, off); ss += __shfl_down(ss, off); }
    const int wave = tid >> 6, lane = tid & 63;
    if (lane == 0) { rs[wave] = s; rss[wave] = ss; }
    __syncthreads();
    if (tid == 0) {
        const float S = rs[0] + rs[1] + rs[2] + rs[3];
        const float SS = rss[0] + rss[1] + rss[2] + rss[3];
        const float mean = S * (1.f / 12800.f);
        const float var = SS * (1.f / 12800.f) - mean * mean;
        const float* gp = h ? g21 : g11;
        const float* bp = h ? b21 : b11;
        const float scale = gp[c] * rsqrtf(var + 1e-5f);
        sc_sh = scale;
        sh_sh = bp[c] - mean * scale;
    }
    __syncthreads();
    const float scale = sc_sh, shift = sh_sh;
    for (int i = tid; i < 12800; i += 256) {
        const int b = i / 200, l = i - b * 200;
        const size_t idx = base + (size_t)b * 6000 + l;
        const float o = A[idx] * scale + shift;
        A[idx] = o;
        Ab[idx] = f2bfu(o);
    }
}

__global__ __launch_bounds__(256) void bn_stage2(const float* __restrict__ A,
                                                 const float* __restrict__ O,
                                                 unsigned short* __restrict__ Cat,
                                                 const float* __restrict__ g12,
                                                 const float* __restrict__ b12,
                                                 const float* __restrict__ g22,
                                                 const float* __restrict__ b22) {
    const int c = blockIdx.x, h = blockIdx.y;
    const int tid = threadIdx.x;
    const size_t base = (size_t)h * 64 * 6000 + c * 200;
    float s = 0.f, ss = 0.f;
    for (int i = tid; i < 12800; i += 256) {
        const int b = i / 200, l = i - b * 200;
        const size_t idx = base + (size_t)b * 6000 + l;
        const float v = A[idx] + O[idx];
        s += v; ss += v * v;
    }
    __shared__ float rs[4], rss[4];
    __shared__ float sc_sh, sh_sh;
    for (int off = 32; off > 0; off >>= 1) { s += __shfl_down(s, off); ss += __shfl_down(ss, off); }
    const int wave = tid >> 6, lane = tid & 63;
    if (lane == 0) { rs[wave] = s; rss[wave] = ss; }
    __syncthreads();
    if (tid == 0) {
        const float S = rs[0] + rs[1] + rs[2] + rs[3];
        const float SS = rss[0] + rss[1] + rss[2] + rss[3];
        const float mean = S * (1.f / 12800.f);
        const float var = SS * (1.f / 12800.f) - mean * mean;
        const float* gp = h ? g22 : g12;
        const float* bp = h ? b22 : b12;
        const float scale = gp[c] * rsqrtf(var + 1e-5f);
        sc_sh = scale;
        sh_sh = bp[c] - mean * scale;
    }
    __syncthreads();
    const float scale = sc_sh, shift = sh_sh;
    for (int i = tid; i < 12800; i += 256) {
        const int b = i / 200, l = i - b * 200;
        const size_t idx = base + (size_t)b * 6000 + l;
        const float o = (A[idx] + O[idx]) * scale + shift;
        Cat[(size_t)b * 12000 + (size_t)h * 6000 + c * 200 + l] = f2bfu(o);
    }
}

// ------------------------------------------- LDS-staged split-K GEMM ----
template <int MT>   // M = MT*16
__global__ __launch_bounds__(256) void gemm_lds_sk(const unsigned short* __restrict__ A,
                                                   const float* __restrict__ W,
                                                   float* __restrict__ P,
                                                   int N, int K,
                                                   int iters_total, int iters_per) {
    constexpr int M = MT * 16;
    constexpr int WB = 64 * 32 * 4;   // 8192 B per buffer (64 rows x 128 B)
    constexpr int AB = M * 32 * 2;    // M*64 B per buffer
    constexpr int ACH = AB / 1024;    // A staging chunks of 1 KB
    __shared__ __align__(16) char lds[2][WB + AB];

    const int tid = threadIdx.x;
    const int wave = tid >> 6;
    const int lane = tid & 63;
    const int r = lane & 15;
    const int g = lane >> 4;
    const int n0 = blockIdx.x * 64;
    const int s = blockIdx.y;
    const int it0 = s * iters_per;
    int it1 = it0 + iters_per;
    if (it1 > iters_total) it1 = iters_total;

    f32x4 acc[MT] = {};
    const u16x8 zu = {};
    const bf16x8 zfrag = __builtin_bit_cast(bf16x8, zu);

    auto stage = [&](int buf, int it) {
        const int k0 = it * 32;
        char* base = &lds[buf][0];
        for (int c = wave; c < 8; c += 4) {
            const int slot = c * 64 + lane;
            const int row = slot >> 3, jj = slot & 7;
            const int j = jj ^ (row & 7);
            int kc = k0 + j * 4;
            if (kc + 4 > K) kc = K - 4;
            int rn = n0 + row;
            if (rn > N - 1) rn = N - 1;
            gload_lds16(W + (size_t)rn * K + kc, base + c * 1024);
        }
        char* abase = base + WB;
        for (int c = wave; c < ACH; c += 4) {
            const int slot = c * 64 + lane;
            const int m = slot >> 2, jj = slot & 3;
            const int j = jj ^ ((m >> 1) & 3);
            int kc = k0 + j * 8;
            if (kc + 8 > K) kc = K - 8;
            gload_lds16(A + (size_t)m * K + kc, abase + c * 1024);
        }
    };

    auto compute = [&](int buf, int it) {
        const int k0 = it * 32;
        const float* Wb = (const float*)&lds[buf][0];
        const unsigned short* Ab = (const unsigned short*)(&lds[buf][0] + WB);
        const int wr = wave * 16 + r;
        const bool ok = (k0 + g * 8 + 8 <= K);
        bf16x8 bfrag = zfrag;
        if (ok) {
            const f32x4* Wrow = (const f32x4*)(Wb + wr * 32);
            const f32x4 x = Wrow[(2 * g) ^ (r & 7)];
            const f32x4 y = Wrow[(2 * g + 1) ^ (r & 7)];
            bfrag = to_bf8(x, y);
        }
#pragma unroll
        for (int mt = 0; mt < MT; ++mt) {
            const int m = mt * 16 + r;
            bf16x8 afrag = zfrag;
            if (ok) {
                afrag = __builtin_bit_cast(
                    bf16x8,
                    ((const u16x8*)(Ab + (size_t)m * 32))[g ^ ((m >> 1) & 3)]);
            }
            acc[mt] = __builtin_amdgcn_mfma_f32_16x16x32_bf16(afrag, bfrag, acc[mt], 0, 0, 0);
        }
    };

    int cur = 0;
    if (it0 < it1) stage(0, it0);
    __syncthreads();
    for (int it = it0; it < it1; ++it) {
        if (it + 1 < it1) stage(cur ^ 1, it + 1);
        compute(cur, it);
        __syncthreads();
        cur ^= 1;
    }

    float* Pp = P + (size_t)s * M * N;
    const int col = n0 + wave * 16 + r;
#pragma unroll
    for (int mt = 0; mt < MT; ++mt) {
#pragma unroll
        for (int rr = 0; rr < 4; ++rr) {
            const int row = mt * 16 + g * 4 + rr;
            if (col < N) Pp[(size_t)row * N + col] = acc[mt][rr];
        }
    }
}

// Sum KS partials + bias -> fp32 or bf16.
template <bool OUT_BF16>
__global__ __launch_bounds__(256) void reduce_bias(const float* __restrict__ P,
                                                   const float* __restrict__ bias,
                                                   int KS, int MN, int N,
                                                   float* __restrict__ of,
                                                   unsigned short* __restrict__ ob) {
    for (int idx = blockIdx.x * 256 + threadIdx.x; idx < MN; idx += gridDim.x * 256) {
        float v = bias[idx % N];
        for (int s = 0; s < KS; ++s) v += P[(size_t)s * MN + idx];
        if constexpr (OUT_BF16) ob[idx] = f2bfu(v);
        else of[idx] = v;
    }
}

// ---------------------------------------------------------------- launch ----
extern "C" void kernel_launch(void* const* d_in, const int* in_sizes, int n_in,
                              void* d_out, int out_size, void* d_ws, size_t ws_size,
                              hipStream_t stream) {
    (void)in_sizes; (void)n_in; (void)out_size;
    const float* X = (const float*)d_in[0];
    ConvArgs ca;
    for (int j = 0; j < 6; ++j) {
        ca.w[j] = (const float*)d_in[1 + 2 * j];
        ca.b[j] = (const float*)d_in[2 + 2 * j];
    }
    const float* bn11_g = (const float*)d_in[13];
    const float* bn11_b = (const float*)d_in[14];
    const float* bn12_g = (const float*)d_in[15];
    const float* bn12_b = (const float*)d_in[16];
    const float* bn21_g = (const float*)d_in[17];
    const float* bn21_b = (const float*)d_in[18];
    const float* bn22_g = (const float*)d_in[19];
    const float* bn22_b = (const float*)d_in[20];
    const float* lin1_w = (const float*)d_in[21];
    const float* lin1_b = (const float*)d_in[22];
    const float* lin2_w = (const float*)d_in[23];
    const float* lin2_b = (const float*)d_in[24];
    const float* cw = (const float*)d_in[25];
    const float* cb = (const float*)d_in[26];
    float* out = (float*)d_out;

    char* w = (char*)d_ws;
    float* A_lin = (float*)w;
    unsigned short* A_bf = (unsigned short*)(w + 3072000);
    char* U = w + 4608000;
    float* convout = (float*)U;
    unsigned short* T_bf = (unsigned short*)U;
    float* O = (float*)(U + 1536000);
    unsigned short* Cat = (unsigned short*)(U + 4608000);
    float* P = (float*)(w + 13824000);

    const size_t avail = ws_size > 13824000 ? ws_size - 13824000 : 0;
    int KS12 = (int)(avail / 3072000);  // per-chunk partials: 128*6000*4 B
    if (KS12 > 12) KS12 = 12;
    if (KS12 < 1) KS12 = 1;
    int KS3 = (int)(avail / 1536000);   // per-chunk partials: 64*6000*4 B
    if (KS3 > 20) KS3 = 20;
    if (KS3 < 1) KS3 = 1;

    conv_all<<<dim3(64, 6), 256, 0, stream>>>(X, ca, convout);
    attn_k<<<dim3(64, 2), 256, 0, stream>>>(convout, X, A_lin);
    bn_stage1<<<dim3(30, 2), 256, 0, stream>>>(A_lin, A_bf, bn11_g, bn11_b, bn21_g, bn21_b);

    {
        const int it_tot = 188;  // ceil(6000/32)
        const int it_per = (it_tot + KS12 - 1) / KS12;
        gemm_lds_sk<8><<<dim3(94, KS12), 256, 0, stream>>>(A_bf, lin1_w, P, 6000, 6000, it_tot, it_per);
        reduce_bias<true><<<dim3(768), 256, 0, stream>>>(P, lin1_b, KS12, 768000, 6000, nullptr, T_bf);
        gemm_lds_sk<8><<<dim3(94, KS12), 256, 0, stream>>>(T_bf, lin2_w, P, 6000, 6000, it_tot, it_per);
        reduce_bias<false><<<dim3(768), 256, 0, stream>>>(P, lin2_b, KS12, 768000, 6000, O, nullptr);
    }

    bn_stage2<<<dim3(30, 2), 256, 0, stream>>>(A_lin, O, Cat, bn12_g, bn12_b, bn22_g, bn22_b);

    {
        const int it_tot = 375;  // 12000/32
        const int it_per = (it_tot + KS3 - 1) / KS3;
        gemm_lds_sk<4><<<dim3(94, KS3), 256, 0, stream>>>(Cat, cw, P, 6000, 12000, it_tot, it_per);
        reduce_bias<false><<<dim3(768), 256, 0, stream>>>(P, cb, KS3, 384000, 6000, out, nullptr);
    }
}

// Round 5
// 306.316 us; speedup vs baseline: 3.4434x; 1.1152x over previous
//
#include <hip/hip_runtime.h>
#include <hip/hip_bf16.h>
#include <math.h>

typedef __attribute__((ext_vector_type(4))) float f32x4;
typedef __attribute__((ext_vector_type(8))) __bf16 bf16x8;
typedef __attribute__((ext_vector_type(8))) unsigned short u16x8;

__device__ __forceinline__ unsigned short f2bfu(float f) {
    unsigned u = __builtin_bit_cast(unsigned, f);
    u += 0x7fffu + ((u >> 16) & 1u);   // RNE
    return (unsigned short)(u >> 16);
}

__device__ __forceinline__ bf16x8 to_bf8(f32x4 x, f32x4 y) {
    bf16x8 o;
#pragma unroll
    for (int j = 0; j < 4; ++j) { o[j] = (__bf16)x[j]; o[j + 4] = (__bf16)y[j]; }
    return o;
}

__device__ __forceinline__ void gload_lds16(const void* g, void* l) {
    __builtin_amdgcn_global_load_lds(
        (__attribute__((address_space(1))) const void*)g,
        (__attribute__((address_space(3))) void*)l, 16, 0, 0);
}

// exact counted waits: keep `newer` stages (VMPS instrs each) in flight
template <int VMPS>
__device__ __forceinline__ void wait_newer(int newer) {
    if (newer >= 2) {
        if constexpr (VMPS == 4) asm volatile("s_waitcnt vmcnt(8)" ::: "memory");
        else                     asm volatile("s_waitcnt vmcnt(6)" ::: "memory");
    } else if (newer == 1) {
        if constexpr (VMPS == 4) asm volatile("s_waitcnt vmcnt(4)" ::: "memory");
        else                     asm volatile("s_waitcnt vmcnt(3)" ::: "memory");
    } else {
        asm volatile("s_waitcnt vmcnt(0)" ::: "memory");
    }
}

// ---------------------------------------------------------------- convs ----
struct ConvArgs {
    const float* w[6];
    const float* b[6];
};

__global__ __launch_bounds__(256) void conv_all(const float* __restrict__ X,
                                                ConvArgs args,
                                                float* __restrict__ out) {
    __shared__ float Xsp[30][208];   // [ci][6 zero-pad + 200 + 2 spare]
    __shared__ float Wg[30][212];    // [c][ci*7+kk]
    const int b = blockIdx.x, j = blockIdx.y;
    const int tid = threadIdx.x;
    const float* xb = X + (size_t)b * 6000;
    for (int i = tid; i < 30 * 208; i += 256) {
        const int ci = i / 208, p = i - ci * 208;
        float v = 0.f;
        if (p >= 6 && p < 206) v = xb[ci * 200 + (p - 6)];
        Xsp[ci][p] = v;
    }
    const float* wsrc = args.w[j];
    for (int i = tid; i < 6300; i += 256) Wg[i / 210][i % 210] = wsrc[i];
    __syncthreads();
    if (tid < 240) {
        const int c = tid >> 3;        // 0..29
        const int strip = tid & 7;     // 0..7
        const int l0 = strip * 25;
        float acc[25];
        const float bias = args.b[j][c];
#pragma unroll
        for (int o = 0; o < 25; ++o) acc[o] = bias;
        for (int ci = 0; ci < 30; ++ci) {
            float wv[7];
#pragma unroll
            for (int kk = 0; kk < 7; ++kk) wv[kk] = Wg[c][ci * 7 + kk];
            float xw[31];
#pragma unroll
            for (int i = 0; i < 31; ++i) xw[i] = Xsp[ci][l0 + i];
#pragma unroll
            for (int o = 0; o < 25; ++o) {
                float a = acc[o];
#pragma unroll
                for (int kk = 0; kk < 7; ++kk) a += xw[o + kk] * wv[kk];
                acc[o] = a;
            }
        }
        float* op = out + ((size_t)j * 64 + b) * 6000 + c * 200 + l0;
#pragma unroll
        for (int o = 0; o < 25; ++o) op[o] = acc[o];
    }
}

// ------------------------------------------------------------ attention ----
__global__ __launch_bounds__(256) void attn_k(const float* __restrict__ conv,
                                              const float* __restrict__ X,
                                              float* __restrict__ A_lin) {
    __shared__ float x1s[30][201], x2s[30][201], x3s[30][201];
    __shared__ float S[5][30][30];
    const int b = blockIdx.x, blk = blockIdx.y;
    const int tid = threadIdx.x;
    const float* c1 = conv + (((size_t)blk * 3 + 0) * 64 + b) * 6000;
    const float* c2 = conv + (((size_t)blk * 3 + 1) * 64 + b) * 6000;
    const float* c3 = conv + (((size_t)blk * 3 + 2) * 64 + b) * 6000;
    for (int i = tid; i < 6000; i += 256) {
        const int c = i / 200, l = i - c * 200;
        x1s[c][l] = c1[i];
        x2s[c][l] = c2[i];
        x3s[c][l] = c3[i];
    }
    __syncthreads();
    const float scale = 7.0710678118654752e-2f;  // 1/sqrt(200)
    if (blk == 0) {
        for (int idx = tid; idx < 900; idx += 256) {
            const int c = idx / 30, d = idx - c * 30;
            float acc = 0.f;
            for (int l = 0; l < 200; ++l) acc += x1s[c][l] * x2s[d][l];
            S[0][c][d] = acc * scale;
        }
    } else {
        for (int idx = tid; idx < 4500; idx += 256) {
            const int h = idx / 900, rem = idx - h * 900;
            const int c = rem / 30, d = rem - c * 30;
            const int base = h * 40;
            float acc = 0.f;
            for (int k = 0; k < 40; ++k) acc += x1s[c][base + k] * x2s[d][base + k];
            S[h][c][d] = acc * scale;
        }
    }
    __syncthreads();
    for (int idx = tid; idx < 6000; idx += 256) {
        const int c = idx / 200, l = idx - c * 200;
        float acc = 0.f;
        if (blk == 0) {
            for (int d = 0; d < 30; ++d) acc += S[0][c][d] * x3s[d][l];
        } else {
            const int h = l / 40;
            for (int d = 0; d < 30; ++d) acc += S[h][c][d] * x3s[d][l];
        }
        const float v = 1.f / (1.f + __expf(-acc)) + X[(size_t)b * 6000 + idx];
        A_lin[((size_t)blk * 64 + b) * 6000 + idx] = v;
    }
}

// ------------------------------------------------------------------- BN ----
__global__ __launch_bounds__(256) void bn_stage1(float* __restrict__ A,
                                                 unsigned short* __restrict__ Ab,
                                                 const float* __restrict__ g11,
                                                 const float* __restrict__ b11,
                                                 const float* __restrict__ g21,
                                                 const float* __restrict__ b21) {
    const int c = blockIdx.x, h = blockIdx.y;
    const int tid = threadIdx.x;
    const size_t base = (size_t)h * 64 * 6000 + c * 200;
    float s = 0.f, ss = 0.f;
    for (int i = tid; i < 12800; i += 256) {
        const int b = i / 200, l = i - b * 200;
        const float v = A[base + (size_t)b * 6000 + l];
        s += v; ss += v * v;
    }
    __shared__ float rs[4], rss[4];
    __shared__ float sc_sh, sh_sh;
    for (int off = 32; off > 0; off >>= 1) { s += __shfl_down(s, off); ss += __shfl_down(ss, off); }
    const int wave = tid >> 6, lane = tid & 63;
    if (lane == 0) { rs[wave] = s; rss[wave] = ss; }
    __syncthreads();
    if (tid == 0) {
        const float S = rs[0] + rs[1] + rs[2] + rs[3];
        const float SS = rss[0] + rss[1] + rss[2] + rss[3];
        const float mean = S * (1.f / 12800.f);
        const float var = SS * (1.f / 12800.f) - mean * mean;
        const float* gp = h ? g21 : g11;
        const float* bp = h ? b21 : b11;
        const float scale = gp[c] * rsqrtf(var + 1e-5f);
        sc_sh = scale;
        sh_sh = bp[c] - mean * scale;
    }
    __syncthreads();
    const float scale = sc_sh, shift = sh_sh;
    for (int i = tid; i < 12800; i += 256) {
        const int b = i / 200, l = i - b * 200;
        const size_t idx = base + (size_t)b * 6000 + l;
        const float o = A[idx] * scale + shift;
        A[idx] = o;
        Ab[idx] = f2bfu(o);
    }
}

__global__ __launch_bounds__(256) void bn_stage2(const float* __restrict__ A,
                                                 const float* __restrict__ O,
                                                 unsigned short* __restrict__ Cat,
                                                 const float* __restrict__ g12,
                                                 const float* __restrict__ b12,
                                                 const float* __restrict__ g22,
                                                 const float* __restrict__ b22) {
    const int c = blockIdx.x, h = blockIdx.y;
    const int tid = threadIdx.x;
    const size_t base = (size_t)h * 64 * 6000 + c * 200;
    float s = 0.f, ss = 0.f;
    for (int i = tid; i < 12800; i += 256) {
        const int b = i / 200, l = i - b * 200;
        const size_t idx = base + (size_t)b * 6000 + l;
        const float v = A[idx] + O[idx];
        s += v; ss += v * v;
    }
    __shared__ float rs[4], rss[4];
    __shared__ float sc_sh, sh_sh;
    for (int off = 32; off > 0; off >>= 1) { s += __shfl_down(s, off); ss += __shfl_down(ss, off); }
    const int wave = tid >> 6, lane = tid & 63;
    if (lane == 0) { rs[wave] = s; rss[wave] = ss; }
    __syncthreads();
    if (tid == 0) {
        const float S = rs[0] + rs[1] + rs[2] + rs[3];
        const float SS = rss[0] + rss[1] + rss[2] + rss[3];
        const float mean = S * (1.f / 12800.f);
        const float var = SS * (1.f / 12800.f) - mean * mean;
        const float* gp = h ? g22 : g12;
        const float* bp = h ? b22 : b12;
        const float scale = gp[c] * rsqrtf(var + 1e-5f);
        sc_sh = scale;
        sh_sh = bp[c] - mean * scale;
    }
    __syncthreads();
    const float scale = sc_sh, shift = sh_sh;
    for (int i = tid; i < 12800; i += 256) {
        const int b = i / 200, l = i - b * 200;
        const size_t idx = base + (size_t)b * 6000 + l;
        const float o = (A[idx] + O[idx]) * scale + shift;
        Cat[(size_t)b * 12000 + (size_t)h * 6000 + c * 200 + l] = f2bfu(o);
    }
}

// --------------------------- depth-3 pipelined split-K GEMM (bf16 P) ----
// P[s][m][n] = sum over k-chunk s of A[m,k]*W[n,k].  A: bf16 [M][K];
// W: fp32 [N][K] (converted in-flight). Block: 4 waves, BN=64 (16 rows/wave),
// all M rows per wave. 3 LDS buffers, counted-vmcnt pipeline (2 stages always
// in flight across barriers; never drain to 0 mid-loop).
template <int MT>   // M = MT*16
__global__ __launch_bounds__(256) void gemm_pipe(const unsigned short* __restrict__ A,
                                                 const float* __restrict__ W,
                                                 unsigned short* __restrict__ P,
                                                 int N, int K,
                                                 int iters_total, int iters_per) {
    constexpr int M = MT * 16;
    constexpr int WB = 64 * 32 * 4;       // 8192 B (64 rows x 128 B)
    constexpr int AB = M * 32 * 2;        // M*64 B
    constexpr int ACH = AB / 1024;        // A chunks (1 KB each)
    constexpr int BUFSZ = WB + AB;
    constexpr int VMPS = 2 + ACH / 4;     // gload_lds instrs per wave per stage
    __shared__ __align__(16) char lds[3][BUFSZ];

    const int tid = threadIdx.x;
    const int wave = tid >> 6;
    const int lane = tid & 63;
    const int r = lane & 15;
    const int g = lane >> 4;
    const int n0 = blockIdx.x * 64;
    const int s = blockIdx.y;
    const int it0 = s * iters_per;
    int it1 = it0 + iters_per;
    if (it1 > iters_total) it1 = iters_total;
    const int nst = it1 - it0;

    f32x4 acc[MT] = {};
    const u16x8 zu = {};
    const bf16x8 zfrag = __builtin_bit_cast(bf16x8, zu);

    auto stage = [&](char* base, int it) {
        const int k0 = it * 32;
#pragma unroll
        for (int u = 0; u < 2; ++u) {           // W: 2 chunks/wave
            const int c = wave + 4 * u;
            const int slot = c * 64 + lane;
            const int row = slot >> 3, jj = slot & 7;
            const int j = jj ^ (row & 7);
            int kc = k0 + j * 4;
            if (kc + 4 > K) kc = K - 4;
            int rn = n0 + row;
            if (rn > N - 1) rn = N - 1;
            gload_lds16(W + (size_t)rn * K + kc, base + c * 1024);
        }
        char* abase = base + WB;
#pragma unroll
        for (int u = 0; u < ACH / 4; ++u) {     // A: ACH/4 chunks/wave
            const int c = wave + 4 * u;
            const int slot = c * 64 + lane;
            const int m = slot >> 2, jj = slot & 3;
            const int j = jj ^ ((m >> 1) & 3);
            int kc = k0 + j * 8;
            if (kc + 8 > K) kc = K - 8;
            gload_lds16(A + (size_t)m * K + kc, abase + c * 1024);
        }
    };

    auto compute = [&](const char* base, int it) {
        const int k0 = it * 32;
        const float* Wb = (const float*)base;
        const unsigned short* Ab = (const unsigned short*)(base + WB);
        const int wr = wave * 16 + r;
        const bool ok = (k0 + g * 8 + 8 <= K);
        bf16x8 bfrag = zfrag;
        if (ok) {
            const f32x4* Wrow = (const f32x4*)(Wb + wr * 32);
            const f32x4 x = Wrow[(2 * g) ^ (r & 7)];
            const f32x4 y = Wrow[(2 * g + 1) ^ (r & 7)];
            bfrag = to_bf8(x, y);
        }
#pragma unroll
        for (int mt = 0; mt < MT; ++mt) {
            const int m = mt * 16 + r;
            bf16x8 afrag = zfrag;
            if (ok) {
                afrag = __builtin_bit_cast(
                    bf16x8,
                    ((const u16x8*)(Ab + (size_t)m * 32))[g ^ ((m >> 1) & 3)]);
            }
            acc[mt] = __builtin_amdgcn_mfma_f32_16x16x32_bf16(afrag, bfrag, acc[mt], 0, 0, 0);
        }
    };

    if (nst > 0) {
        // prologue: stage up to 3 tiles
        const int p = nst < 3 ? nst : 3;
        for (int i = 0; i < p; ++i) stage(&lds[i][0], it0 + i);
        wait_newer<VMPS>(p - 1);
        __builtin_amdgcn_s_barrier();
        __builtin_amdgcn_sched_barrier(0);

        int bi = 0;
        for (int it = it0; it < it1; ++it) {
            compute(&lds[bi][0], it);
            __builtin_amdgcn_sched_barrier(0);
            __builtin_amdgcn_s_barrier();          // all waves done reading buf bi
            if (it + 3 < it1) stage(&lds[bi][0], it + 3);
            if (it + 1 < it1) {
                const int newer = (it + 3 <= it1 - 1) ? 2 : (it1 - 1) - (it + 1);
                wait_newer<VMPS>(newer);           // oldest pending stage done
                __builtin_amdgcn_s_barrier();
                __builtin_amdgcn_sched_barrier(0);
            }
            bi = bi == 2 ? 0 : bi + 1;
        }
    }

    unsigned short* Pp = P + (size_t)s * M * N;
    const int col = n0 + wave * 16 + r;
#pragma unroll
    for (int mt = 0; mt < MT; ++mt) {
#pragma unroll
        for (int rr = 0; rr < 4; ++rr) {
            const int row = mt * 16 + g * 4 + rr;
            if (col < N) Pp[(size_t)row * N + col] = f2bfu(acc[mt][rr]);
        }
    }
}

// Sum KS bf16 partials + bias -> fp32 or bf16.
template <bool OUT_BF16>
__global__ __launch_bounds__(256) void reduce_bias(const unsigned short* __restrict__ P,
                                                   const float* __restrict__ bias,
                                                   int KS, int MN, int N,
                                                   float* __restrict__ of,
                                                   unsigned short* __restrict__ ob) {
    for (int idx = blockIdx.x * 256 + threadIdx.x; idx < MN; idx += gridDim.x * 256) {
        float v = bias[idx % N];
        for (int s = 0; s < KS; ++s) {
            const unsigned u = P[(size_t)s * MN + idx];
            v += __builtin_bit_cast(float, u << 16);
        }
        if constexpr (OUT_BF16) ob[idx] = f2bfu(v);
        else of[idx] = v;
    }
}

// ---------------------------------------------------------------- launch ----
extern "C" void kernel_launch(void* const* d_in, const int* in_sizes, int n_in,
                              void* d_out, int out_size, void* d_ws, size_t ws_size,
                              hipStream_t stream) {
    (void)in_sizes; (void)n_in; (void)out_size;
    const float* X = (const float*)d_in[0];
    ConvArgs ca;
    for (int j = 0; j < 6; ++j) {
        ca.w[j] = (const float*)d_in[1 + 2 * j];
        ca.b[j] = (const float*)d_in[2 + 2 * j];
    }
    const float* bn11_g = (const float*)d_in[13];
    const float* bn11_b = (const float*)d_in[14];
    const float* bn12_g = (const float*)d_in[15];
    const float* bn12_b = (const float*)d_in[16];
    const float* bn21_g = (const float*)d_in[17];
    const float* bn21_b = (const float*)d_in[18];
    const float* bn22_g = (const float*)d_in[19];
    const float* bn22_b = (const float*)d_in[20];
    const float* lin1_w = (const float*)d_in[21];
    const float* lin1_b = (const float*)d_in[22];
    const float* lin2_w = (const float*)d_in[23];
    const float* lin2_b = (const float*)d_in[24];
    const float* cw = (const float*)d_in[25];
    const float* cb = (const float*)d_in[26];
    float* out = (float*)d_out;

    char* w = (char*)d_ws;
    float* A_lin = (float*)w;
    unsigned short* A_bf = (unsigned short*)(w + 3072000);
    char* U = w + 4608000;
    float* convout = (float*)U;
    unsigned short* T_bf = (unsigned short*)U;
    float* O = (float*)(U + 1536000);
    unsigned short* Cat = (unsigned short*)(U + 4608000);
    unsigned short* P = (unsigned short*)(w + 13824000);

    const size_t avail = ws_size > 13824000 ? ws_size - 13824000 : 0;
    int KS12 = (int)(avail / 1536000);  // per-chunk bf16 partials: 128*6000*2 B
    if (KS12 > 8) KS12 = 8;
    if (KS12 < 1) KS12 = 1;
    int KS3 = (int)(avail / 768000);    // per-chunk bf16 partials: 64*6000*2 B
    if (KS3 > 11) KS3 = 11;
    if (KS3 < 1) KS3 = 1;

    conv_all<<<dim3(64, 6), 256, 0, stream>>>(X, ca, convout);
    attn_k<<<dim3(64, 2), 256, 0, stream>>>(convout, X, A_lin);
    bn_stage1<<<dim3(30, 2), 256, 0, stream>>>(A_lin, A_bf, bn11_g, bn11_b, bn21_g, bn21_b);

    {
        const int it_tot = 188;  // ceil(6000/32)
        const int it_per = (it_tot + KS12 - 1) / KS12;
        gemm_pipe<8><<<dim3(94, KS12), 256, 0, stream>>>(A_bf, lin1_w, P, 6000, 6000, it_tot, it_per);
        reduce_bias<true><<<dim3(768), 256, 0, stream>>>(P, lin1_b, KS12, 768000, 6000, nullptr, T_bf);
        gemm_pipe<8><<<dim3(94, KS12), 256, 0, stream>>>(T_bf, lin2_w, P, 6000, 6000, it_tot, it_per);
        reduce_bias<false><<<dim3(768), 256, 0, stream>>>(P, lin2_b, KS12, 768000, 6000, O, nullptr);
    }

    bn_stage2<<<dim3(30, 2), 256, 0, stream>>>(A_lin, O, Cat, bn12_g, bn12_b, bn22_g, bn22_b);

    {
        const int it_tot = 375;  // 12000/32
        const int it_per = (it_tot + KS3 - 1) / KS3;
        gemm_pipe<4><<<dim3(94, KS3), 256, 0, stream>>>(Cat, cw, P, 6000, 12000, it_tot, it_per);
        reduce_bias<false><<<dim3(768), 256, 0, stream>>>(P, cb, KS3, 384000, 6000, out, nullptr);
    }
}